// Round 6
// baseline (269.736 us; speedup 1.0000x reference)
//
#include <hip/hip_runtime.h>
#include <stdint.h>

// Causal SDPA B=4,H=16,S=2048,D=64 fp32. Flash-MFMA bf16, round 6.
// convert_prep: UNCHANGED (control; part of the fixed ~114us floor).
// sdpa_mfma v6: 32q waves, 4096 waves (1024 blocks x 256 thr) = 16 waves/CU.
//   Pair chain (c, 63-c) = 33 key-block steps exactly; split 17/16 over 2 waves;
//   block hosts 2 chains; ONE barrier at end, merge partial (O,l) via LDS.
//   P C-layout -> A-layout transform done IN-REGISTER via ds_bpermute
//   (no P LDS storage, no round-trip latency, no bank conflicts).
//   K/V^T fragments loaded directly from global bf16 (L2-resident).

#define SLEN 2048
#define DHEAD 64
#define NHEADS 64
#define NELEM (SLEN * DHEAD * NHEADS)   // 8388608 per tensor

typedef short bf16x8 __attribute__((ext_vector_type(8)));
typedef float f32x4 __attribute__((ext_vector_type(4)));

__device__ __forceinline__ uint32_t pkbf(float hi, float lo) {
    uint32_t a = __builtin_bit_cast(uint32_t, lo) + 0x8000u;
    uint32_t b = __builtin_bit_cast(uint32_t, hi) + 0x8000u;
    return __builtin_amdgcn_perm(b, a, 0x07060302u);
}
__device__ __forceinline__ unsigned short f2bf(float f) {
    return (unsigned short)((__builtin_bit_cast(uint32_t, f) + 0x8000u) >> 16);
}

// ---------------- pass 1: K straight, V transposed (identical to rounds 3-5) ----------------
__global__ __launch_bounds__(256)
void convert_prep(const float* __restrict__ K, const float* __restrict__ V,
                  unsigned short* __restrict__ Kb, unsigned short* __restrict__ Vtb) {
    __shared__ unsigned short Lt[64 * 264];
    const int b = blockIdx.x, t = threadIdx.x;
    if (b < 4096) {
        const int off = (b * 256 + t) * 8;
        float4 a = *(const float4*)(K + off);
        float4 c = *(const float4*)(K + off + 4);
        uint4 o;
        o.x = pkbf(a.y, a.x); o.y = pkbf(a.w, a.z);
        o.z = pkbf(c.y, c.x); o.w = pkbf(c.w, c.z);
        *(uint4*)(Kb + off) = o;
    } else {
        const int vb2 = b - 4096;
        const int head = vb2 >> 3, kblk = vb2 & 7;
        const float* Vh = V + (size_t)head * (SLEN * DHEAD) + kblk * 256 * DHEAD;
        unsigned short* Vo = Vtb + (size_t)head * (SLEN * DHEAD) + kblk * 256;
#pragma unroll
        for (int i = 0; i < 16; ++i) {
            int idx = t + 256 * i;
            int key = idx >> 4, d4 = idx & 15;
            float4 v = *(const float4*)(Vh + key * DHEAD + d4 * 4);
            Lt[(d4 * 4 + 0) * 264 + key] = f2bf(v.x);
            Lt[(d4 * 4 + 1) * 264 + key] = f2bf(v.y);
            Lt[(d4 * 4 + 2) * 264 + key] = f2bf(v.z);
            Lt[(d4 * 4 + 3) * 264 + key] = f2bf(v.w);
        }
        __syncthreads();
#pragma unroll
        for (int jj = 0; jj < 8; ++jj) {
            int idx = t + 256 * jj;
            int d = idx >> 5, k8 = idx & 31;
            *(uint4*)(Vo + (size_t)d * SLEN + k8 * 8) = *(const uint4*)(Lt + d * 264 + k8 * 8);
        }
    }
}

// ---------------- pass 2: flash attention, bpermute P-transform ----------------
__global__ __launch_bounds__(256, 4)
void sdpa_mfma(const float* __restrict__ Qf, const unsigned short* __restrict__ Kb,
               const unsigned short* __restrict__ Vtb, float* __restrict__ Og) {
    const int n = blockIdx.x;
    const int head = n & 63;
    const int cp = n >> 6;                 // 0..15
    const int tid = threadIdx.x;
    const int w = tid >> 6, lane = tid & 63;
    const int cl = lane & 15, quad = lane >> 4;
    const int ch = w >> 1, role = w & 1;   // chain in block, role in chain
    const int c = cp + 16 * ch;            // chain id 0..31
    const int subA = c, subB = 63 - c;     // 32q subtile indices
    const int Sa = (c >> 1) + 1;           // key-blocks for subA
    const int Sb = ((63 - c) >> 1) + 1;    // key-blocks for subB; Sa+Sb == 33

    const size_t hb = (size_t)head * SLEN * DHEAD;
    const float* Qh = Qf + hb;
    const unsigned short* Kh = Kb + hb;    // [key][d]
    const unsigned short* Vth = Vtb + hb;  // [d][key]
    float* Oh = Og + hb;

    __shared__ float Om[2][64 * 36];       // merge buffer [chain][col d][row q], pad 36
    __shared__ float Lsm[2][32];

    // bpermute source-lane indices: lane_s = cl + 16*(2*(quad&1) + (dp>>1))
    const int idx0 = 4 * (cl + 32 * (quad & 1));
    const int idx1 = idx0 + 64;
    const float SCL = 0.18033688f;         // (1/sqrt(64)) * log2(e), folded into Q

    bf16x8 qf[2][2];
    f32x4 o[2][4];
    float ls[2];

    auto load_qf = [&](int i) {
#pragma unroll
        for (int m = 0; m < 2; ++m)
#pragma unroll
            for (int h = 0; h < 2; ++h) {
                const float* src = Qh + (size_t)(i * 32 + m * 16 + cl) * DHEAD + h * 32 + quad * 8;
                float4 a = *(const float4*)src;
                float4 b = *(const float4*)(src + 4);
                uint4 u;
                u.x = pkbf(a.y * SCL, a.x * SCL); u.y = pkbf(a.w * SCL, a.z * SCL);
                u.z = pkbf(b.y * SCL, b.x * SCL); u.w = pkbf(b.w * SCL, b.z * SCL);
                qf[m][h] = __builtin_bit_cast(bf16x8, u);
            }
    };
    auto zero_acc = [&]() {
#pragma unroll
        for (int m = 0; m < 2; ++m) {
            ls[m] = 0.f;
#pragma unroll
            for (int d = 0; d < 4; ++d) o[m][d] = (f32x4){0.f, 0.f, 0.f, 0.f};
        }
    };

    // key-blocks [js,je) of 32q-subtile i (queries [32i,32i+32))
    auto do_steps = [&](int i, int js, int je) {
        const int jd = i >> 1;             // diagonal key-block
        const int qrb = 32 * (i & 1);
        for (int j = js; j < je; ++j) {
            const unsigned short* kbase = Kh + (size_t)j * 64 * DHEAD;
            bf16x8 kb[4][2];
#pragma unroll
            for (int kk = 0; kk < 4; ++kk)
#pragma unroll
                for (int h = 0; h < 2; ++h)
                    kb[kk][h] = __builtin_bit_cast(bf16x8,
                        *(const uint4*)(kbase + (kk * 16 + cl) * DHEAD + h * 32 + quad * 8));
            const unsigned short* vbase = Vth + j * 64;
            bf16x8 vb0[4];
#pragma unroll
            for (int dd = 0; dd < 4; ++dd)
                vb0[dd] = __builtin_bit_cast(bf16x8,
                    *(const uint4*)(vbase + (size_t)(dd * 16 + cl) * SLEN + quad * 8));

            uint32_t Sd[2][4][2];          // packed P^T: [qq][kk][pair-of-4-keys]
            const bool partial = (j == jd);
#pragma unroll
            for (int kk = 0; kk < 4; ++kk) {
                const int krel = kk * 16 + quad * 4;
#pragma unroll
                for (int qq = 0; qq < 2; ++qq) {
                    f32x4 s = (f32x4){0.f, 0.f, 0.f, 0.f};
                    s = __builtin_amdgcn_mfma_f32_16x16x32_bf16(kb[kk][0], qf[qq][0], s, 0, 0, 0);
                    s = __builtin_amdgcn_mfma_f32_16x16x32_bf16(kb[kk][1], qf[qq][1], s, 0, 0, 0);
                    float p0, p1, p2, p3;
                    if (partial) {
                        const int qrel = qrb + qq * 16 + cl;
                        p0 = (krel + 0 <= qrel) ? __builtin_amdgcn_exp2f(s[0]) : 0.f;
                        p1 = (krel + 1 <= qrel) ? __builtin_amdgcn_exp2f(s[1]) : 0.f;
                        p2 = (krel + 2 <= qrel) ? __builtin_amdgcn_exp2f(s[2]) : 0.f;
                        p3 = (krel + 3 <= qrel) ? __builtin_amdgcn_exp2f(s[3]) : 0.f;
                    } else {
                        p0 = __builtin_amdgcn_exp2f(s[0]);
                        p1 = __builtin_amdgcn_exp2f(s[1]);
                        p2 = __builtin_amdgcn_exp2f(s[2]);
                        p3 = __builtin_amdgcn_exp2f(s[3]);
                    }
                    ls[qq] += (p0 + p1) + (p2 + p3);
                    Sd[qq][kk][0] = pkbf(p1, p0);
                    Sd[qq][kk][1] = pkbf(p3, p2);
                }
            }
            bf16x8 vb1[4];
#pragma unroll
            for (int dd = 0; dd < 4; ++dd)
                vb1[dd] = __builtin_bit_cast(bf16x8,
                    *(const uint4*)(vbase + (size_t)(dd * 16 + cl) * SLEN + 32 + quad * 8));

            // C-layout -> A-layout in-register: pa[qq][h] dword dp holds keys
            // h*32 + quad*8 + 2dp + {0,1}; src lane cl+16*(2(quad&1)+(dp>>1)),
            // src reg kk = 2h + (quad>>1) selected by cndmask.
            bf16x8 pa[2][2];
#pragma unroll
            for (int qq = 0; qq < 2; ++qq)
#pragma unroll
                for (int h = 0; h < 2; ++h) {
                    uint32_t dw[4];
#pragma unroll
                    for (int dp = 0; dp < 4; ++dp) {
                        const int id = (dp < 2) ? idx0 : idx1;
                        int ra = __builtin_amdgcn_ds_bpermute(id, (int)Sd[qq][2 * h][dp & 1]);
                        int rb = __builtin_amdgcn_ds_bpermute(id, (int)Sd[qq][2 * h + 1][dp & 1]);
                        dw[dp] = (quad < 2) ? (uint32_t)ra : (uint32_t)rb;
                    }
                    uint4 u; u.x = dw[0]; u.y = dw[1]; u.z = dw[2]; u.w = dw[3];
                    pa[qq][h] = __builtin_bit_cast(bf16x8, u);
                }
#pragma unroll
            for (int m = 0; m < 2; ++m)
#pragma unroll
                for (int dd = 0; dd < 4; ++dd) {
                    o[m][dd] = __builtin_amdgcn_mfma_f32_16x16x32_bf16(pa[m][0], vb0[dd], o[m][dd], 0, 0, 0);
                    o[m][dd] = __builtin_amdgcn_mfma_f32_16x16x32_bf16(pa[m][1], vb1[dd], o[m][dd], 0, 0, 0);
                }
        }
    };
    auto reduce_ls = [&]() {
#pragma unroll
        for (int qq = 0; qq < 2; ++qq) {
            float v = ls[qq];
            v += __shfl_xor(v, 16);
            v += __shfl_xor(v, 32);
            ls[qq] = v;
        }
    };
    auto store_tile = [&](int i, const float* lsr) {
#pragma unroll
        for (int m = 0; m < 2; ++m)
#pragma unroll
            for (int r = 0; r < 4; ++r) {
                const float inv = 1.0f / __shfl(lsr[m], quad * 4 + r);
#pragma unroll
                for (int dd = 0; dd < 4; ++dd)
                    Oh[(size_t)(i * 32 + m * 16 + quad * 4 + r) * DHEAD + dd * 16 + cl] = o[m][dd][r] * inv;
            }
    };

    if (role == 0) {
        load_qf(subA); zero_acc();
        do_steps(subA, 0, Sa);             // subtile A complete (diag last)
        reduce_ls();
        store_tile(subA, ls);
        load_qf(subB); zero_acc();
        do_steps(subB, 0, Sb - 16);        // subtile B head (all full blocks)
        reduce_ls();
    } else {
        load_qf(subB); zero_acc();
        do_steps(subB, Sb - 16, Sb);       // subtile B tail (diag last)
        reduce_ls();
#pragma unroll
        for (int m = 0; m < 2; ++m)
#pragma unroll
            for (int dd = 0; dd < 4; ++dd)
                *(f32x4*)&Om[ch][(dd * 16 + cl) * 36 + m * 16 + quad * 4] = o[m][dd];
        if (quad == 0) {
#pragma unroll
            for (int qq = 0; qq < 2; ++qq) Lsm[ch][qq * 16 + cl] = ls[qq];
        }
    }
    __syncthreads();
    if (role == 0) {
#pragma unroll
        for (int m = 0; m < 2; ++m)
#pragma unroll
            for (int dd = 0; dd < 4; ++dd)
                o[m][dd] += *(const f32x4*)&Om[ch][(dd * 16 + cl) * 36 + m * 16 + quad * 4];
        float lc[2];
#pragma unroll
        for (int qq = 0; qq < 2; ++qq) lc[qq] = ls[qq] + Lsm[ch][qq * 16 + cl];
        store_tile(subB, lc);
    }
}

extern "C" void kernel_launch(void* const* d_in, const int* in_sizes, int n_in,
                              void* d_out, int out_size, void* d_ws, size_t ws_size,
                              hipStream_t stream) {
    const float* Q = (const float*)d_in[0];
    const float* K = (const float*)d_in[1];
    const float* V = (const float*)d_in[2];
    float*       O = (float*)d_out;

    unsigned short* Kbf  = (unsigned short*)d_ws;
    unsigned short* Vtbf = Kbf + NELEM;

    convert_prep<<<dim3(4096 + 512), dim3(256), 0, stream>>>(K, V, Kbf, Vtbf);
    sdpa_mfma<<<dim3(1024), dim3(256), 0, stream>>>(Q, Kbf, Vtbf, O);
}